// Round 8
// baseline (331.060 us; speedup 1.0000x reference)
//
#include <hip/hip_runtime.h>
#include <math.h>

#define NHEADS 16
#define HDIM   64
#define HID    1024
#define BATCH  2
#define SEQ    2048
#define NX (BATCH*SEQ*HID)       // 4194304
#define NW (HID*HID)             // 1048576

typedef unsigned short u16;
typedef __attribute__((ext_vector_type(8))) short  bf16x8;   // 8 bf16 = 4 VGPR
typedef __attribute__((ext_vector_type(8))) unsigned short u16x8;
typedef __attribute__((ext_vector_type(4))) float  f32x4;

// ---------------------------------------------------------------------------
// Fragment-tiled layout ("FT"): operand rows r, inner dim k. Subtile =
// 16 rows x 32 k. Element (r,k) lives at
//   ((r>>4)*KB + (k>>5))*512 + ((k>>3)&3)*128 + (r&15)*8 + (k&7)     [u16]
// (KB = k-blocks per row-block row). A wave's MFMA fragment load
// (lane = quad*16+lx -> 16B) is then 64 lanes x 16B CONTIGUOUS: perfectly
// coalesced global_load_dwordx4, no LDS round-trip needed.
// hi / lo planes are separate arrays (keeps lane stride 16B).
// ---------------------------------------------------------------------------

// v_perm-based split: hi pair = bytes[2,3] of each fp32 (truncated bf16),
// lo pair = bytes[2,3] of (p - hi) — numerically identical to shift form.
__device__ __forceinline__ void split8(const float* xf, bf16x8& hi, bf16x8& lo) {
    unsigned* hp = (unsigned*)&hi;
    unsigned* lp = (unsigned*)&lo;
#pragma unroll
    for (int j = 0; j < 4; j++) {
        const float p0 = xf[2 * j], p1 = xf[2 * j + 1];
        const unsigned u0 = __float_as_uint(p0);
        const unsigned u1 = __float_as_uint(p1);
        hp[j] = __builtin_amdgcn_perm(u1, u0, 0x07060302u);
        const float l0 = p0 - __uint_as_float(u0 & 0xFFFF0000u);
        const float l1 = p1 - __uint_as_float(u1 & 0xFFFF0000u);
        lp[j] = __builtin_amdgcn_perm(__float_as_uint(l1), __float_as_uint(l0), 0x07060302u);
    }
}
__device__ __forceinline__ void split1(float v, u16& h, u16& l) {
    unsigned u = __float_as_uint(v);
    h = (u16)(u >> 16);
    l = (u16)(__float_as_uint(v - __uint_as_float(u & 0xFFFF0000u)) >> 16);
}

// ---------------------------------------------------------------------------
// RoPE tables
// ---------------------------------------------------------------------------
__global__ void rope_tables_kernel(float* __restrict__ ct, float* __restrict__ st) {
    int idx = blockIdx.x * 256 + threadIdx.x;
    if (idx >= SEQ * HDIM) return;
    int s  = idx >> 6;
    int dh = idx & 63;
    int i  = dh & 31;
    float inv = exp2f(-(float)i * (13.28771237954945f / 32.0f));  // log2(10000)/32
    float fr  = (float)s * inv;
    ct[idx] = cosf(fr);
    st[idx] = sinf(fr);
}

// ---------------------------------------------------------------------------
// Pre-pass: split X and W0/1/2 fp32 -> bf16 hi/lo planes, FRAG-TILED (KB=32).
// ---------------------------------------------------------------------------
__global__ void split_kernel(const float* __restrict__ X,
                             const float* __restrict__ W0,
                             const float* __restrict__ W1,
                             const float* __restrict__ W2,
                             u16* __restrict__ Xhi, u16* __restrict__ Xlo,
                             u16* __restrict__ Whi, u16* __restrict__ Wlo)
{
    long idx = ((long)blockIdx.x * 256 + threadIdx.x) * 4;
    if (idx >= (long)NX + 3L * NW) return;
    const float* src; u16* dh; u16* dl; long off;
    if (idx < NX) { src = X; dh = Xhi; dl = Xlo; off = idx; }
    else {
        long rr = idx - NX;
        int wi = (int)(rr >> 20);
        off = rr & (NW - 1);
        src = (wi == 0) ? W0 : ((wi == 1) ? W1 : W2);
        dh = Whi + (size_t)wi * NW;
        dl = Wlo + (size_t)wi * NW;
    }
    const int r = (int)(off >> 10);
    const int k = (int)(off & 1023);
    // frag-tiled offset (KB=32):
    const size_t fo = ((size_t)(r >> 4) * 32 + (k >> 5)) * 512
                    + (size_t)((k >> 3) & 3) * 128 + (size_t)(r & 15) * 8 + (k & 7);
    float4 v = *(const float4*)(src + off);
    const float* vf = (const float*)&v;
    ushort4 h4, l4;
    u16* hp = (u16*)&h4; u16* lp = (u16*)&l4;
#pragma unroll
    for (int e = 0; e < 4; e++) split1(vf[e], hp[e], lp[e]);
    *(ushort4*)(dh + fo) = h4;
    *(ushort4*)(dl + fo) = l4;
}

// ---------------------------------------------------------------------------
// MFMA QKV GEMM, NO LDS / NO BARRIERS in the K-loop: fragments loaded
// directly from frag-tiled global, register double-buffered.
// v7 (unchanged): XCD n-ownership remap + manual 2x-unrolled K-loop with
// buffer role swap + s_setprio around the MFMA clusters.
// ---------------------------------------------------------------------------
__global__ __launch_bounds__(256, 2) void qkv_mfma_kernel(
    const u16* __restrict__ Xhi, const u16* __restrict__ Xlo,
    const u16* __restrict__ Whi, const u16* __restrict__ Wlo,
    const float* __restrict__ ct, const float* __restrict__ st,
    u16* __restrict__ Qhi, u16* __restrict__ Qlo,
    u16* __restrict__ Khi, u16* __restrict__ Klo,
    u16* __restrict__ Vhi, u16* __restrict__ Vlo)
{
    __shared__ unsigned vtr[64][129];   // proj-2 transpose buffer only

    const int t    = threadIdx.x;
    const int lane = t & 63;
    const int w    = t >> 6;
    const int lx   = lane & 15;
    const int quad = lane >> 4;

    // XCD n-ownership remap (768 blocks, 1D): xcd = lid%8 owns n-panel xcd.
    const int lid  = blockIdx.x;
    const int xcd  = lid & 7;
    const int i_   = lid >> 3;          // 0..95
    const int proj = i_ % 3;
    const int mb   = i_ / 3;            // 0..31
    const int nb   = xcd;
    const int n0   = nb * 128;
    const int m0   = mb * 128;

    const u16* __restrict__ Wph = Whi + (size_t)proj * NW;
    const u16* __restrict__ Wpl = Wlo + (size_t)proj * NW;

    const int am = (w & 1) * 64;
    const int bn = (w >> 1) * 64;
    const int lp = quad * 128 + lx * 8;        // lane part of frag offset

    const u16 *pAh[4], *pAl[4], *pBh[4], *pBl[4];
#pragma unroll
    for (int i = 0; i < 4; i++) {
        const size_t o = ((size_t)(((m0 + am) >> 4) + i) * 32) * 512 + lp;
        pAh[i] = Xhi + o; pAl[i] = Xlo + o;
    }
#pragma unroll
    for (int j = 0; j < 4; j++) {
        const size_t o = ((size_t)(((n0 + bn) >> 4) + j) * 32) * 512 + lp;
        pBh[j] = Wph + o; pBl[j] = Wpl + o;
    }

    f32x4 acc[4][4];
#pragma unroll
    for (int i = 0; i < 4; i++)
#pragma unroll
        for (int j = 0; j < 4; j++) acc[i][j] = (f32x4){0.f, 0.f, 0.f, 0.f};

    bf16x8 cah[4], cal[4], cbh[4], cbl[4];
    bf16x8 nah[4], nal[4], nbh[4], nbl[4];
    // prefetch k-block 0 into c-buffers
#pragma unroll
    for (int i = 0; i < 4; i++) { cah[i] = *(const bf16x8*)(pAh[i]); cal[i] = *(const bf16x8*)(pAl[i]); }
#pragma unroll
    for (int j = 0; j < 4; j++) { cbh[j] = *(const bf16x8*)(pBh[j]); cbl[j] = *(const bf16x8*)(pBl[j]); }

#pragma unroll 1
    for (int kt = 0; kt < HID; kt += 64) {
        const int ko1 = ((kt + 32) >> 5) * 512;
        const int ko2 = (kt + 64 < HID) ? ((kt + 64) >> 5) * 512 : 0;

        // prefetch k-block kt+32 into n-buffers
#pragma unroll
        for (int i = 0; i < 4; i++) { nah[i] = *(const bf16x8*)(pAh[i] + ko1); nal[i] = *(const bf16x8*)(pAl[i] + ko1); }
#pragma unroll
        for (int j = 0; j < 4; j++) { nbh[j] = *(const bf16x8*)(pBh[j] + ko1); nbl[j] = *(const bf16x8*)(pBl[j] + ko1); }

        __builtin_amdgcn_s_setprio(1);
#pragma unroll
        for (int j = 0; j < 4; j++)
#pragma unroll
            for (int i = 0; i < 4; i++) {
                acc[i][j] = __builtin_amdgcn_mfma_f32_16x16x32_bf16(cah[i], cbh[j], acc[i][j], 0, 0, 0);
                acc[i][j] = __builtin_amdgcn_mfma_f32_16x16x32_bf16(cal[i], cbh[j], acc[i][j], 0, 0, 0);
                acc[i][j] = __builtin_amdgcn_mfma_f32_16x16x32_bf16(cah[i], cbl[j], acc[i][j], 0, 0, 0);
            }
        __builtin_amdgcn_s_setprio(0);

        // prefetch k-block kt+64 into c-buffers
#pragma unroll
        for (int i = 0; i < 4; i++) { cah[i] = *(const bf16x8*)(pAh[i] + ko2); cal[i] = *(const bf16x8*)(pAl[i] + ko2); }
#pragma unroll
        for (int j = 0; j < 4; j++) { cbh[j] = *(const bf16x8*)(pBh[j] + ko2); cbl[j] = *(const bf16x8*)(pBl[j] + ko2); }

        __builtin_amdgcn_s_setprio(1);
#pragma unroll
        for (int j = 0; j < 4; j++)
#pragma unroll
            for (int i = 0; i < 4; i++) {
                acc[i][j] = __builtin_amdgcn_mfma_f32_16x16x32_bf16(nah[i], nbh[j], acc[i][j], 0, 0, 0);
                acc[i][j] = __builtin_amdgcn_mfma_f32_16x16x32_bf16(nal[i], nbh[j], acc[i][j], 0, 0, 0);
                acc[i][j] = __builtin_amdgcn_mfma_f32_16x16x32_bf16(nah[i], nbl[j], acc[i][j], 0, 0, 0);
            }
        __builtin_amdgcn_s_setprio(0);
    }

    // ---- epilogue ----
    const int b      = m0 >> 11;
    const int head   = (n0 >> 6) + (w >> 1);
    const int m_base = m0 + am;

    if (proj < 2) {
        // RoPE in registers: partner dh^32 = acc[i][j^2], same lane.
#pragma unroll
        for (int i = 0; i < 4; i++) {
#pragma unroll
            for (int r = 0; r < 4; r++) {
                const int s = (m_base + i * 16 + quad * 4 + r) & 2047;
                const float* ctr = ct + s * HDIM;
                const float* str = st + s * HDIM;
                float nv[4];
#pragma unroll
                for (int j = 0; j < 4; j++) {
                    const int dh = j * 16 + lx;
                    const float c  = ctr[dh];
                    const float sn = str[dh];
                    const float x  = acc[i][j][r];
                    const float p  = acc[i][j ^ 2][r];
                    nv[j] = (j < 2) ? (x * c - p * sn) : (x * c + p * sn);
                }
#pragma unroll
                for (int j = 0; j < 4; j++) acc[i][j][r] = nv[j];
            }
        }
        // store Q or K, frag-tiled (rows=s, k=dh, KB=2)
        u16* dh_ = (proj == 0) ? Qhi : Khi;
        u16* dl_ = (proj == 0) ? Qlo : Klo;
        const float qscale = (proj == 0) ? 0.18033688011112042f : 1.0f;
        const size_t obase = (size_t)(b * NHEADS + head) * SEQ * HDIM;
#pragma unroll
        for (int i = 0; i < 4; i++)
#pragma unroll
            for (int r = 0; r < 4; r++) {
                const int s   = (m_base + i * 16 + quad * 4 + r) & 2047;
                const int rb  = s >> 4;
                const int lxq = s & 15;
#pragma unroll
                for (int j = 0; j < 4; j++) {
                    const size_t fo = obase + ((size_t)rb * 2 + (j >> 1)) * 512
                                    + (size_t)((j & 1) * 2 + (lx >> 3)) * 128
                                    + (size_t)lxq * 8 + (lx & 7);
                    u16 hh, ll;
                    split1(acc[i][j][r] * qscale, hh, ll);
                    dh_[fo] = hh;
                    dl_[fo] = ll;
                }
            }
    } else {
        // V: two-pass LDS transpose -> frag-tiled V^T (rows=d, k=s, KB=64)
#pragma unroll 1
        for (int pass = 0; pass < 2; pass++) {
            __syncthreads();
            if ((w & 1) == pass) {
#pragma unroll
                for (int i = 0; i < 4; i++)
#pragma unroll
                    for (int j = 0; j < 4; j++)
#pragma unroll
                        for (int r = 0; r < 4; r++) {
                            const int ml = i * 16 + quad * 4 + r;
                            const int nl = bn + j * 16 + lx;
                            const float v = acc[i][j][r];
                            unsigned u  = __float_as_uint(v);
                            unsigned hi = u & 0xFFFF0000u;
                            unsigned lo = __float_as_uint(v - __uint_as_float(hi)) >> 16;
                            vtr[ml][nl] = hi | lo;
                        }
            }
            __syncthreads();
            {
                const int d      = t >> 1;            // 0..127 (2 heads x 64)
                const int sh     = (t & 1) * 32;
                const int headv  = (n0 >> 6) + (d >> 6);
                const int dd     = d & 63;
                const size_t vbase = (size_t)(b * NHEADS + headv) * SEQ * HDIM;
                const int s0base = (m0 & 2047) + pass * 64 + sh;
#pragma unroll
                for (int k = 0; k < 4; k++) {
                    const int s0 = s0base + k * 8;
                    u16x8 hv, lv;
#pragma unroll
                    for (int e = 0; e < 8; e++) {
                        unsigned u = vtr[sh + k * 8 + e][d];
                        hv[e] = (u16)(u >> 16);
                        lv[e] = (u16)(u & 0xFFFFu);
                    }
                    const size_t fo = vbase + ((size_t)(dd >> 4) * 64 + (s0 >> 5)) * 512
                                    + (size_t)((s0 >> 3) & 3) * 128 + (size_t)(dd & 15) * 8;
                    *(u16x8*)(Vhi + fo) = hv;
                    *(u16x8*)(Vlo + fo) = lv;
                }
            }
        }
    }
}

// ---------------------------------------------------------------------------
// Flash attention v9: 128-q blocks (round-5 structure) with SWAPPED QK^T.
// Computing mfma(K, Q) instead of mfma(Q, K) makes each lane hold 4
// CONSECUTIVE kv values of one q row (q = lx, kv = c*16+quad*4+r), so the
// P-store to LDS becomes ONE ds_write_b128 per (a,c) instead of 4 scalar
// ds_write_b32 — the PS round-trip was the saturated LDS-unit resource
// (MfmaUtil invariant at ~28% across a=1/a=2 rounds). PS memory layout
// [q][kv] is unchanged -> PV read path and epilogue identical.
// l is accumulated in-lane (each lane owns one q's partial sum) and
// reduced with 2 shfl_xor at the end.
// Register K double-buffer + V-early pipeline + setprio kept from round 6.
// Q arrives pre-scaled by log2(e)/8, so scores feed exp2 directly.
// ---------------------------------------------------------------------------
__global__ __launch_bounds__(256, 2) void attn_kernel(
    const u16* __restrict__ Qhi, const u16* __restrict__ Qlo,
    const u16* __restrict__ Khi, const u16* __restrict__ Klo,
    const u16* __restrict__ Vhi, const u16* __restrict__ Vlo,
    float* __restrict__ OUT)
{
    __shared__ float PS[4][32][68];

    const int t    = threadIdx.x;
    const int lane = t & 63;
    const int w    = t >> 6;
    const int lx   = lane & 15;
    const int quad = lane >> 4;

    const int q0 = blockIdx.x * 128;
    const int h  = blockIdx.y;
    const int b  = blockIdx.z;
    const size_t base = (size_t)(b * NHEADS + h) * SEQ * HDIM;
    const int lp = quad * 128 + lx * 8;

    // Q fragments (already split + pre-scaled in workspace)
    bf16x8 qh[2][2], ql[2][2];
#pragma unroll
    for (int a = 0; a < 2; a++)
#pragma unroll
        for (int ks = 0; ks < 2; ks++) {
            const size_t fo = base + ((size_t)((q0 >> 4) + w * 2 + a) * 2 + ks) * 512 + lp;
            qh[a][ks] = *(const bf16x8*)(Qhi + fo);
            ql[a][ks] = *(const bf16x8*)(Qlo + fo);
        }

    f32x4 O[2][4];
    float l_s[2];                       // in-lane partial sum for q = a*16+lx
#pragma unroll
    for (int a = 0; a < 2; a++) {
#pragma unroll
        for (int dt = 0; dt < 4; dt++) O[a][dt] = (f32x4){0.f,0.f,0.f,0.f};
        l_s[a] = 0.f;
    }

    // K double-buffer (A/B), prologue fills A with tile 0
    bf16x8 kAh[2][4], kAl[2][4], kBh[2][4], kBl[2][4];
#pragma unroll
    for (int c = 0; c < 4; c++)
#pragma unroll
        for (int ks = 0; ks < 2; ks++) {
            const size_t fo = base + ((size_t)c * 2 + ks) * 512 + lp;
            kAh[ks][c] = *(const bf16x8*)(Khi + fo);
            kAl[ks][c] = *(const bf16x8*)(Klo + fo);
        }

    // one kv-tile: consume (ckh,ckl) for tile kt, prefetch tile ktn into (nkh,nkl)
    auto tile_body = [&](bf16x8 (&ckh)[2][4], bf16x8 (&ckl)[2][4],
                         bf16x8 (&nkh)[2][4], bf16x8 (&nkl)[2][4],
                         int kt, int ktn) {
        // ---- V fragment loads (issued first; consumed after QK+exp) ----
        bf16x8 vh[2][4], vl[2][4];
#pragma unroll
        for (int dt = 0; dt < 4; dt++)
#pragma unroll
            for (int ks2 = 0; ks2 < 2; ks2++) {
                const size_t fo = base + ((size_t)dt * 64 + (kt >> 5) + ks2) * 512 + lp;
                vh[ks2][dt] = *(const bf16x8*)(Vhi + fo);
                vl[ks2][dt] = *(const bf16x8*)(Vlo + fo);
            }

        // ---- swapped scores: lane holds S[kv=c*16+quad*4+r][q=a*16+lx] ----
#pragma unroll
        for (int a = 0; a < 2; a++) {
#pragma unroll
            for (int c = 0; c < 4; c++) {
                f32x4 acc = (f32x4){0.f,0.f,0.f,0.f};
                __builtin_amdgcn_s_setprio(1);
#pragma unroll
                for (int ks = 0; ks < 2; ks++) {
                    acc = __builtin_amdgcn_mfma_f32_16x16x32_bf16(ckh[ks][c], qh[a][ks], acc, 0, 0, 0);
                    acc = __builtin_amdgcn_mfma_f32_16x16x32_bf16(ckh[ks][c], ql[a][ks], acc, 0, 0, 0);
                    acc = __builtin_amdgcn_mfma_f32_16x16x32_bf16(ckl[ks][c], qh[a][ks], acc, 0, 0, 0);
                }
                __builtin_amdgcn_s_setprio(0);
                f32x4 p4;
#pragma unroll
                for (int r = 0; r < 4; r++) p4[r] = exp2f(acc[r]);  // Q pre-scaled
                l_s[a] += (p4[0] + p4[1]) + (p4[2] + p4[3]);
                // 4 consecutive kv for one q -> single b128 store
                *(f32x4*)&PS[w][a * 16 + lx][c * 16 + quad * 4] = p4;
            }
        }

        // ---- prefetch next tile's K into alternate buffer ----
#pragma unroll
        for (int c = 0; c < 4; c++)
#pragma unroll
            for (int ks = 0; ks < 2; ks++) {
                const size_t fo = base + ((size_t)((ktn >> 4) + c) * 2 + ks) * 512 + lp;
                nkh[ks][c] = *(const bf16x8*)(Khi + fo);
                nkl[ks][c] = *(const bf16x8*)(Klo + fo);
            }

        // ---- PV (unchanged: PS layout [q][kv] identical) ----
#pragma unroll
        for (int a = 0; a < 2; a++) {
#pragma unroll
            for (int ks2 = 0; ks2 < 2; ks2++) {
                const float* ps = &PS[w][a * 16 + lx][ks2 * 32 + quad * 8];
                float pf[8];
                *(float4*)&pf[0] = *(const float4*)ps;
                *(float4*)&pf[4] = *(const float4*)(ps + 4);
                bf16x8 phi, plo;
                split8(pf, phi, plo);
                __builtin_amdgcn_s_setprio(1);
#pragma unroll
                for (int dt = 0; dt < 4; dt++) {
                    O[a][dt] = __builtin_amdgcn_mfma_f32_16x16x32_bf16(phi, vh[ks2][dt], O[a][dt], 0, 0, 0);
                    O[a][dt] = __builtin_amdgcn_mfma_f32_16x16x32_bf16(plo, vh[ks2][dt], O[a][dt], 0, 0, 0);
                    O[a][dt] = __builtin_amdgcn_mfma_f32_16x16x32_bf16(phi, vl[ks2][dt], O[a][dt], 0, 0, 0);
                }
                __builtin_amdgcn_s_setprio(0);
            }
        }
    };

#pragma unroll 1
    for (int kt = 0; kt < SEQ; kt += 128) {
        tile_body(kAh, kAl, kBh, kBl, kt,       kt + 64);
        tile_body(kBh, kBl, kAh, kAl, kt + 64, (kt + 128) & (SEQ - 1));
    }

    // full l per q = a*16+lx lives split across the 4 quads: xor-reduce
    float lfin[2];
#pragma unroll
    for (int a = 0; a < 2; a++) {
        float l = l_s[a];
        l += __shfl_xor(l, 16);
        l += __shfl_xor(l, 32);
        lfin[a] = l;
    }
    // O rows are q = a*16 + quad*4 + r: pull the matching l via shfl
    float linv[2][4];
#pragma unroll
    for (int a = 0; a < 2; a++)
#pragma unroll
        for (int r = 0; r < 4; r++)
            linv[a][r] = 1.f / __shfl(lfin[a], quad * 4 + r);

    float* Po = &PS[0][0][0];   // reuse as [128][68]
    __syncthreads();            // all waves done with their PS regions
#pragma unroll
    for (int a = 0; a < 2; a++)
#pragma unroll
        for (int dt = 0; dt < 4; dt++)
#pragma unroll
            for (int r = 0; r < 4; r++)
                Po[(size_t)(w * 32 + a * 16 + quad * 4 + r) * 68 + dt * 16 + lx] =
                    O[a][dt][r] * linv[a][r];
    __syncthreads();
    {
        const int q    = t >> 1;
        const int half = t & 1;
        const float* prow = Po + (size_t)q * 68 + half * 32;
        float* dst = OUT + ((size_t)(b * SEQ + q0 + q)) * HID + h * HDIM + half * 32;
#pragma unroll
        for (int e = 0; e < 8; e++)
            ((float4*)dst)[e] = ((const float4*)prow)[e];
    }
}

// ---------------------------------------------------------------------------
extern "C" void kernel_launch(void* const* d_in, const int* in_sizes, int n_in,
                              void* d_out, int out_size, void* d_ws, size_t ws_size,
                              hipStream_t stream)
{
    const float* X  = (const float*)d_in[0];
    const float* Wq = (const float*)d_in[1];
    const float* Wk = (const float*)d_in[2];
    const float* Wv = (const float*)d_in[3];
    float* out = (float*)d_out;

    const size_t qkv_elems = (size_t)BATCH * NHEADS * SEQ * HDIM;  // 4,194,304
    char* wsb = (char*)d_ws;
    float* ct  = (float*)wsb;                       // 0.5 MB
    float* st  = ct + (size_t)SEQ * HDIM;           // 0.5 MB
    u16* Xhi = (u16*)(st + (size_t)SEQ * HDIM);     // 8 MB
    u16* Xlo = Xhi + (size_t)NX;                    // 8 MB
    u16* Whi = Xlo + (size_t)NX;                    // 6 MB
    u16* Wlo = Whi + 3 * (size_t)NW;                // 6 MB
    u16* Qhi = Wlo + 3 * (size_t)NW;                // 8 MB
    u16* Qlo = Qhi + qkv_elems;                     // 8 MB
    u16* Khi = Qlo + qkv_elems;                     // 8 MB
    u16* Klo = Khi + qkv_elems;                     // 8 MB
    u16* Vhi = Klo + qkv_elems;                     // 8 MB
    u16* Vlo = Vhi + qkv_elems;                     // 8 MB   (total 77 MB)

    rope_tables_kernel<<<(SEQ * HDIM + 255) / 256, 256, 0, stream>>>(ct, st);

    const long tot = (long)NX + 3L * NW;
    split_kernel<<<(int)((tot / 4 + 255) / 256), 256, 0, stream>>>(
        X, Wq, Wk, Wv, Xhi, Xlo, Whi, Wlo);

    qkv_mfma_kernel<<<dim3(3 * (HID / 128) * ((BATCH * SEQ) / 128)), 256, 0, stream>>>(
        Xhi, Xlo, Whi, Wlo, ct, st, Qhi, Qlo, Khi, Klo, Vhi, Vlo);

    attn_kernel<<<dim3(SEQ / 128, NHEADS, BATCH), 256, 0, stream>>>(
        Qhi, Qlo, Khi, Klo, Vhi, Vlo, out);
}

// Round 9
// 268.204 us; speedup vs baseline: 1.2344x; 1.2344x over previous
//
#include <hip/hip_runtime.h>
#include <math.h>

#define NHEADS 16
#define HDIM   64
#define HID    1024
#define BATCH  2
#define SEQ    2048
#define NX (BATCH*SEQ*HID)       // 4194304
#define NW (HID*HID)             // 1048576

typedef unsigned short u16;
typedef __attribute__((ext_vector_type(8))) short  bf16x8;   // 8 bf16 = 4 VGPR
typedef __attribute__((ext_vector_type(8))) unsigned short u16x8;
typedef __attribute__((ext_vector_type(4))) float  f32x4;

// ---------------------------------------------------------------------------
// Fragment-tiled layout ("FT"): operand rows r, inner dim k. Subtile =
// 16 rows x 32 k. Element (r,k) lives at
//   ((r>>4)*KB + (k>>5))*512 + ((k>>3)&3)*128 + (r&15)*8 + (k&7)     [u16]
// (KB = k-blocks per row-block row). A wave's MFMA fragment load
// (lane = quad*16+lx -> 16B) is then 64 lanes x 16B CONTIGUOUS.
// hi / lo planes are separate arrays (keeps lane stride 16B).
// ---------------------------------------------------------------------------

// v_perm-based split: hi pair = bytes[2,3] of each fp32 (truncated bf16),
// lo pair = bytes[2,3] of (p - hi) — numerically identical to shift form.
__device__ __forceinline__ void split8(const float* xf, bf16x8& hi, bf16x8& lo) {
    unsigned* hp = (unsigned*)&hi;
    unsigned* lp = (unsigned*)&lo;
#pragma unroll
    for (int j = 0; j < 4; j++) {
        const float p0 = xf[2 * j], p1 = xf[2 * j + 1];
        const unsigned u0 = __float_as_uint(p0);
        const unsigned u1 = __float_as_uint(p1);
        hp[j] = __builtin_amdgcn_perm(u1, u0, 0x07060302u);
        const float l0 = p0 - __uint_as_float(u0 & 0xFFFF0000u);
        const float l1 = p1 - __uint_as_float(u1 & 0xFFFF0000u);
        lp[j] = __builtin_amdgcn_perm(__float_as_uint(l1), __float_as_uint(l0), 0x07060302u);
    }
}
__device__ __forceinline__ void split1(float v, u16& h, u16& l) {
    unsigned u = __float_as_uint(v);
    h = (u16)(u >> 16);
    l = (u16)(__float_as_uint(v - __uint_as_float(u & 0xFFFF0000u)) >> 16);
}

// ---------------------------------------------------------------------------
// RoPE tables
// ---------------------------------------------------------------------------
__global__ void rope_tables_kernel(float* __restrict__ ct, float* __restrict__ st) {
    int idx = blockIdx.x * 256 + threadIdx.x;
    if (idx >= SEQ * HDIM) return;
    int s  = idx >> 6;
    int dh = idx & 63;
    int i  = dh & 31;
    float inv = exp2f(-(float)i * (13.28771237954945f / 32.0f));  // log2(10000)/32
    float fr  = (float)s * inv;
    ct[idx] = cosf(fr);
    st[idx] = sinf(fr);
}

// ---------------------------------------------------------------------------
// Pre-pass v2: split fp32 -> bf16 hi/lo planes, frag-tiled. One WAVE per
// 512-u16 subtile: lane l = (q=l>>4, r=l&15) reads 8 consecutive floats of
// row R0+r at col K0+q*8 and writes ONE ushort8 at lane-contiguous offset
// l*8 -> perfectly coalesced 1KB wave-stores (old version scattered ushort4
// at 256B stride -> partial-line write amplification).
// Subtiles: X = 8192, then 3 x 2048 for W0/1/2. Grid = 14336/4 = 3584.
// ---------------------------------------------------------------------------
__global__ __launch_bounds__(256) void split_kernel(
    const float* __restrict__ X,
    const float* __restrict__ W0,
    const float* __restrict__ W1,
    const float* __restrict__ W2,
    u16* __restrict__ Xhi, u16* __restrict__ Xlo,
    u16* __restrict__ Whi, u16* __restrict__ Wlo)
{
    const int s = blockIdx.x * 4 + (threadIdx.x >> 6);
    const int l = threadIdx.x & 63;
    const int r = l & 15, q = l >> 4;
    const float* src; u16* dh; u16* dl; int so;
    if (s < 8192) { src = X; dh = Xhi; dl = Xlo; so = s; }
    else {
        const int wi = (s - 8192) >> 11;
        so = (s - 8192) & 2047;
        src = (wi == 0) ? W0 : ((wi == 1) ? W1 : W2);
        dh = Whi + (size_t)wi * NW;
        dl = Wlo + (size_t)wi * NW;
    }
    const int R0 = (so >> 5) << 4, K0 = (so & 31) << 5;
    const float* sp = src + (size_t)(R0 + r) * 1024 + K0 + q * 8;
    float v[8];
    *(float4*)&v[0] = *(const float4*)sp;
    *(float4*)&v[4] = *(const float4*)(sp + 4);
    u16x8 h8, l8;
#pragma unroll
    for (int e = 0; e < 8; e++) {
        u16 hh, ll;
        split1(v[e], hh, ll);
        h8[e] = hh; l8[e] = ll;
    }
    const size_t off = (size_t)so * 512 + l * 8;
    *(u16x8*)(dh + off) = h8;
    *(u16x8*)(dl + off) = l8;
}

// ---------------------------------------------------------------------------
// MFMA QKV GEMM (unchanged from round 6): no LDS in K-loop, frag-tiled
// global fragments, XCD n-ownership remap, 2x-unrolled role-swapped
// register double-buffer, s_setprio around MFMA clusters.
// ---------------------------------------------------------------------------
__global__ __launch_bounds__(256, 2) void qkv_mfma_kernel(
    const u16* __restrict__ Xhi, const u16* __restrict__ Xlo,
    const u16* __restrict__ Whi, const u16* __restrict__ Wlo,
    const float* __restrict__ ct, const float* __restrict__ st,
    u16* __restrict__ Qhi, u16* __restrict__ Qlo,
    u16* __restrict__ Khi, u16* __restrict__ Klo,
    u16* __restrict__ Vhi, u16* __restrict__ Vlo)
{
    __shared__ unsigned vtr[64][129];   // proj-2 transpose buffer only

    const int t    = threadIdx.x;
    const int lane = t & 63;
    const int w    = t >> 6;
    const int lx   = lane & 15;
    const int quad = lane >> 4;

    // XCD n-ownership remap (768 blocks, 1D): xcd = lid%8 owns n-panel xcd.
    const int lid  = blockIdx.x;
    const int xcd  = lid & 7;
    const int i_   = lid >> 3;          // 0..95
    const int proj = i_ % 3;
    const int mb   = i_ / 3;            // 0..31
    const int nb   = xcd;
    const int n0   = nb * 128;
    const int m0   = mb * 128;

    const u16* __restrict__ Wph = Whi + (size_t)proj * NW;
    const u16* __restrict__ Wpl = Wlo + (size_t)proj * NW;

    const int am = (w & 1) * 64;
    const int bn = (w >> 1) * 64;
    const int lp = quad * 128 + lx * 8;        // lane part of frag offset

    const u16 *pAh[4], *pAl[4], *pBh[4], *pBl[4];
#pragma unroll
    for (int i = 0; i < 4; i++) {
        const size_t o = ((size_t)(((m0 + am) >> 4) + i) * 32) * 512 + lp;
        pAh[i] = Xhi + o; pAl[i] = Xlo + o;
    }
#pragma unroll
    for (int j = 0; j < 4; j++) {
        const size_t o = ((size_t)(((n0 + bn) >> 4) + j) * 32) * 512 + lp;
        pBh[j] = Wph + o; pBl[j] = Wpl + o;
    }

    f32x4 acc[4][4];
#pragma unroll
    for (int i = 0; i < 4; i++)
#pragma unroll
        for (int j = 0; j < 4; j++) acc[i][j] = (f32x4){0.f, 0.f, 0.f, 0.f};

    bf16x8 cah[4], cal[4], cbh[4], cbl[4];
    bf16x8 nah[4], nal[4], nbh[4], nbl[4];
#pragma unroll
    for (int i = 0; i < 4; i++) { cah[i] = *(const bf16x8*)(pAh[i]); cal[i] = *(const bf16x8*)(pAl[i]); }
#pragma unroll
    for (int j = 0; j < 4; j++) { cbh[j] = *(const bf16x8*)(pBh[j]); cbl[j] = *(const bf16x8*)(pBl[j]); }

#pragma unroll 1
    for (int kt = 0; kt < HID; kt += 64) {
        const int ko1 = ((kt + 32) >> 5) * 512;
        const int ko2 = (kt + 64 < HID) ? ((kt + 64) >> 5) * 512 : 0;

#pragma unroll
        for (int i = 0; i < 4; i++) { nah[i] = *(const bf16x8*)(pAh[i] + ko1); nal[i] = *(const bf16x8*)(pAl[i] + ko1); }
#pragma unroll
        for (int j = 0; j < 4; j++) { nbh[j] = *(const bf16x8*)(pBh[j] + ko1); nbl[j] = *(const bf16x8*)(pBl[j] + ko1); }

        __builtin_amdgcn_s_setprio(1);
#pragma unroll
        for (int j = 0; j < 4; j++)
#pragma unroll
            for (int i = 0; i < 4; i++) {
                acc[i][j] = __builtin_amdgcn_mfma_f32_16x16x32_bf16(cah[i], cbh[j], acc[i][j], 0, 0, 0);
                acc[i][j] = __builtin_amdgcn_mfma_f32_16x16x32_bf16(cal[i], cbh[j], acc[i][j], 0, 0, 0);
                acc[i][j] = __builtin_amdgcn_mfma_f32_16x16x32_bf16(cah[i], cbl[j], acc[i][j], 0, 0, 0);
            }
        __builtin_amdgcn_s_setprio(0);

#pragma unroll
        for (int i = 0; i < 4; i++) { cah[i] = *(const bf16x8*)(pAh[i] + ko2); cal[i] = *(const bf16x8*)(pAl[i] + ko2); }
#pragma unroll
        for (int j = 0; j < 4; j++) { cbh[j] = *(const bf16x8*)(pBh[j] + ko2); cbl[j] = *(const bf16x8*)(pBl[j] + ko2); }

        __builtin_amdgcn_s_setprio(1);
#pragma unroll
        for (int j = 0; j < 4; j++)
#pragma unroll
            for (int i = 0; i < 4; i++) {
                acc[i][j] = __builtin_amdgcn_mfma_f32_16x16x32_bf16(nah[i], nbh[j], acc[i][j], 0, 0, 0);
                acc[i][j] = __builtin_amdgcn_mfma_f32_16x16x32_bf16(nal[i], nbh[j], acc[i][j], 0, 0, 0);
                acc[i][j] = __builtin_amdgcn_mfma_f32_16x16x32_bf16(nah[i], nbl[j], acc[i][j], 0, 0, 0);
            }
        __builtin_amdgcn_s_setprio(0);
    }

    // ---- epilogue ----
    const int b      = m0 >> 11;
    const int head   = (n0 >> 6) + (w >> 1);
    const int m_base = m0 + am;

    if (proj < 2) {
#pragma unroll
        for (int i = 0; i < 4; i++) {
#pragma unroll
            for (int r = 0; r < 4; r++) {
                const int s = (m_base + i * 16 + quad * 4 + r) & 2047;
                const float* ctr = ct + s * HDIM;
                const float* str = st + s * HDIM;
                float nv[4];
#pragma unroll
                for (int j = 0; j < 4; j++) {
                    const int dh = j * 16 + lx;
                    const float c  = ctr[dh];
                    const float sn = str[dh];
                    const float x  = acc[i][j][r];
                    const float p  = acc[i][j ^ 2][r];
                    nv[j] = (j < 2) ? (x * c - p * sn) : (x * c + p * sn);
                }
#pragma unroll
                for (int j = 0; j < 4; j++) acc[i][j][r] = nv[j];
            }
        }
        u16* dh_ = (proj == 0) ? Qhi : Khi;
        u16* dl_ = (proj == 0) ? Qlo : Klo;
        const float qscale = (proj == 0) ? 0.18033688011112042f : 1.0f;
        const size_t obase = (size_t)(b * NHEADS + head) * SEQ * HDIM;
#pragma unroll
        for (int i = 0; i < 4; i++)
#pragma unroll
            for (int r = 0; r < 4; r++) {
                const int s   = (m_base + i * 16 + quad * 4 + r) & 2047;
                const int rb  = s >> 4;
                const int lxq = s & 15;
#pragma unroll
                for (int j = 0; j < 4; j++) {
                    const size_t fo = obase + ((size_t)rb * 2 + (j >> 1)) * 512
                                    + (size_t)((j & 1) * 2 + (lx >> 3)) * 128
                                    + (size_t)lxq * 8 + (lx & 7);
                    u16 hh, ll;
                    split1(acc[i][j][r] * qscale, hh, ll);
                    dh_[fo] = hh;
                    dl_[fo] = ll;
                }
            }
    } else {
#pragma unroll 1
        for (int pass = 0; pass < 2; pass++) {
            __syncthreads();
            if ((w & 1) == pass) {
#pragma unroll
                for (int i = 0; i < 4; i++)
#pragma unroll
                    for (int j = 0; j < 4; j++)
#pragma unroll
                        for (int r = 0; r < 4; r++) {
                            const int ml = i * 16 + quad * 4 + r;
                            const int nl = bn + j * 16 + lx;
                            const float v = acc[i][j][r];
                            unsigned u  = __float_as_uint(v);
                            unsigned hi = u & 0xFFFF0000u;
                            unsigned lo = __float_as_uint(v - __uint_as_float(hi)) >> 16;
                            vtr[ml][nl] = hi | lo;
                        }
            }
            __syncthreads();
            {
                const int d      = t >> 1;            // 0..127 (2 heads x 64)
                const int sh     = (t & 1) * 32;
                const int headv  = (n0 >> 6) + (d >> 6);
                const int dd     = d & 63;
                const size_t vbase = (size_t)(b * NHEADS + headv) * SEQ * HDIM;
                const int s0base = (m0 & 2047) + pass * 64 + sh;
#pragma unroll
                for (int k = 0; k < 4; k++) {
                    const int s0 = s0base + k * 8;
                    u16x8 hv, lv;
#pragma unroll
                    for (int e = 0; e < 8; e++) {
                        unsigned u = vtr[sh + k * 8 + e][d];
                        hv[e] = (u16)(u >> 16);
                        lv[e] = (u16)(u & 0xFFFFu);
                    }
                    const size_t fo = vbase + ((size_t)(dd >> 4) * 64 + (s0 >> 5)) * 512
                                    + (size_t)((s0 >> 3) & 3) * 128 + (size_t)(dd & 15) * 8;
                    *(u16x8*)(Vhi + fo) = hv;
                    *(u16x8*)(Vlo + fo) = lv;
                }
            }
        }
    }
}

// ---------------------------------------------------------------------------
// Flash attention v10: round-5 compute core (128-q blocks, unswapped QK,
// V-early, PS[4][32][68] round-trip) but K/V fragments come from LDS:
// per kv-tile, Khi/Klo/Vhi (24 KB) are staged cooperatively (6 b128 global
// loads + 6 ds_writes per thread), then every wave ds_read_b128's its
// fragments — removes the 4x-redundant per-wave global K/V loads and the
// compiler's fragile 32-outstanding-load vmcnt pipeline. Vlo stays a direct
// global load (8/wave) to keep LDS = 59392 B (<= 64 KB with PS unchanged).
// Staging loads for tile t+1 issue right after barrier-2 and are consumed
// at the next barrier -> __syncthreads' vmcnt(0) drain waits on nothing.
// Q arrives pre-scaled by log2(e)/8, so scores feed exp2 directly.
// ---------------------------------------------------------------------------
__global__ __launch_bounds__(256, 2) void attn_kernel(
    const u16* __restrict__ Qhi, const u16* __restrict__ Qlo,
    const u16* __restrict__ Khi, const u16* __restrict__ Klo,
    const u16* __restrict__ Vhi, const u16* __restrict__ Vlo,
    float* __restrict__ OUT)
{
    __shared__ __align__(16) u16 KVs[3][4096];   // Khi, Klo, Vhi tiles (24 KB)
    __shared__ float PS[4][32][68];              // 34816 B

    const int t    = threadIdx.x;
    const int lane = t & 63;
    const int w    = t >> 6;
    const int lx   = lane & 15;
    const int quad = lane >> 4;

    const int q0 = blockIdx.x * 128;
    const int h  = blockIdx.y;
    const int b  = blockIdx.z;
    const size_t base = (size_t)(b * NHEADS + h) * SEQ * HDIM;
    const int lp = quad * 128 + lx * 8;

    // Q fragments (already split + pre-scaled in workspace)
    bf16x8 qh[2][2], ql[2][2];
#pragma unroll
    for (int a = 0; a < 2; a++)
#pragma unroll
        for (int ks = 0; ks < 2; ks++) {
            const size_t fo = base + ((size_t)((q0 >> 4) + w * 2 + a) * 2 + ks) * 512 + lp;
            qh[a][ks] = *(const bf16x8*)(Qhi + fo);
            ql[a][ks] = *(const bf16x8*)(Qlo + fo);
        }

    f32x4 O[2][4];
    float l_part[2][4];
#pragma unroll
    for (int a = 0; a < 2; a++) {
#pragma unroll
        for (int dt = 0; dt < 4; dt++) O[a][dt] = (f32x4){0.f,0.f,0.f,0.f};
#pragma unroll
        for (int r = 0; r < 4; r++) l_part[a][r] = 0.f;
    }

    // --- staging machinery: thread handles 6 16B chunks per tile ---
    // chunk i: plane p = i>>1 (0=Khi 1=Klo 2=Vhi), in-plane u16 off
    // o = (((i&1)<<8)+t)*8 covering [0,4096) per plane.
    u16x8 sreg[6];
    auto stage_load = [&](int kt) {
#pragma unroll
        for (int i = 0; i < 6; i++) {
            const int o = (((i & 1) << 8) + t) * 8;
            const u16* g;
            if (i < 2)      g = Khi + base + (size_t)(kt >> 4) * 1024 + o;
            else if (i < 4) g = Klo + base + (size_t)(kt >> 4) * 1024 + o;
            else {
                const int dt = o >> 10, rem = o & 1023;
                g = Vhi + base + ((size_t)dt * 64 + (kt >> 5)) * 512 + rem;
            }
            sreg[i] = *(const u16x8*)g;
        }
    };

    stage_load(0);

#pragma unroll 1
    for (int kt = 0; kt < SEQ; kt += 64) {
        __syncthreads();                       // prev body done reading KVs
#pragma unroll
        for (int i = 0; i < 6; i++) {
            const int o = (((i & 1) << 8) + t) * 8;
            *(u16x8*)&KVs[i >> 1][o] = sreg[i];
        }
        __syncthreads();                       // staging visible

        // issue next tile's staging loads (consumed at next barrier)
        stage_load((kt + 64) & (SEQ - 1));

        // ---- Vlo fragments: direct global (early issue, consumed in PV) ----
        bf16x8 vl[2][4];
#pragma unroll
        for (int dt = 0; dt < 4; dt++)
#pragma unroll
            for (int ks2 = 0; ks2 < 2; ks2++)
                vl[ks2][dt] = *(const bf16x8*)(Vlo + base + ((size_t)dt * 64 + (kt >> 5) + ks2) * 512 + lp);

        // ---- K fragments from LDS ----
        bf16x8 kh[2][4], kl[2][4];
#pragma unroll
        for (int c = 0; c < 4; c++)
#pragma unroll
            for (int ks = 0; ks < 2; ks++) {
                kh[ks][c] = *(const bf16x8*)&KVs[0][(c * 2 + ks) * 512 + lp];
                kl[ks][c] = *(const bf16x8*)&KVs[1][(c * 2 + ks) * 512 + lp];
            }

        // ---- scores + exp -> PS ----
#pragma unroll
        for (int a = 0; a < 2; a++) {
#pragma unroll
            for (int c = 0; c < 4; c++) {
                f32x4 acc = (f32x4){0.f,0.f,0.f,0.f};
                __builtin_amdgcn_s_setprio(1);
#pragma unroll
                for (int ks = 0; ks < 2; ks++) {
                    acc = __builtin_amdgcn_mfma_f32_16x16x32_bf16(qh[a][ks], kh[ks][c], acc, 0, 0, 0);
                    acc = __builtin_amdgcn_mfma_f32_16x16x32_bf16(ql[a][ks], kh[ks][c], acc, 0, 0, 0);
                    acc = __builtin_amdgcn_mfma_f32_16x16x32_bf16(qh[a][ks], kl[ks][c], acc, 0, 0, 0);
                }
                __builtin_amdgcn_s_setprio(0);
#pragma unroll
                for (int r = 0; r < 4; r++) {
                    float p = exp2f(acc[r]);           // Q pre-scaled: 2^(qk*log2e/8)
                    l_part[a][r] += p;
                    PS[w][a * 16 + quad * 4 + r][c * 16 + lx] = p;
                }
            }
        }

        // ---- Vhi fragments from LDS ----
        bf16x8 vh[2][4];
#pragma unroll
        for (int dt = 0; dt < 4; dt++)
#pragma unroll
            for (int ks2 = 0; ks2 < 2; ks2++)
                vh[ks2][dt] = *(const bf16x8*)&KVs[2][dt * 1024 + ks2 * 512 + lp];

        // ---- PV ----
#pragma unroll
        for (int a = 0; a < 2; a++) {
#pragma unroll
            for (int ks2 = 0; ks2 < 2; ks2++) {
                const float* ps = &PS[w][a * 16 + lx][ks2 * 32 + quad * 8];
                float pf[8];
                *(float4*)&pf[0] = *(const float4*)ps;
                *(float4*)&pf[4] = *(const float4*)(ps + 4);
                bf16x8 phi, plo;
                split8(pf, phi, plo);
                __builtin_amdgcn_s_setprio(1);
#pragma unroll
                for (int dt = 0; dt < 4; dt++) {
                    O[a][dt] = __builtin_amdgcn_mfma_f32_16x16x32_bf16(phi, vh[ks2][dt], O[a][dt], 0, 0, 0);
                    O[a][dt] = __builtin_amdgcn_mfma_f32_16x16x32_bf16(plo, vh[ks2][dt], O[a][dt], 0, 0, 0);
                    O[a][dt] = __builtin_amdgcn_mfma_f32_16x16x32_bf16(phi, vl[ks2][dt], O[a][dt], 0, 0, 0);
                }
                __builtin_amdgcn_s_setprio(0);
            }
        }
    }

    float linv[2][4];
#pragma unroll
    for (int a = 0; a < 2; a++)
#pragma unroll
        for (int r = 0; r < 4; r++) {
            float l = l_part[a][r];
            l += __shfl_xor(l, 1);
            l += __shfl_xor(l, 2);
            l += __shfl_xor(l, 4);
            l += __shfl_xor(l, 8);
            linv[a][r] = 1.f / l;
        }

    float* Po = &PS[0][0][0];   // reuse as [128][68]
    __syncthreads();            // all waves done with their PS regions
#pragma unroll
    for (int a = 0; a < 2; a++)
#pragma unroll
        for (int dt = 0; dt < 4; dt++)
#pragma unroll
            for (int r = 0; r < 4; r++)
                Po[(size_t)(w * 32 + a * 16 + quad * 4 + r) * 68 + dt * 16 + lx] =
                    O[a][dt][r] * linv[a][r];
    __syncthreads();
    {
        const int q    = t >> 1;
        const int half = t & 1;
        const float* prow = Po + (size_t)q * 68 + half * 32;
        float* dst = OUT + ((size_t)(b * SEQ + q0 + q)) * HID + h * HDIM + half * 32;
#pragma unroll
        for (int e = 0; e < 8; e++)
            ((float4*)dst)[e] = ((const float4*)prow)[e];
    }
}

// ---------------------------------------------------------------------------
extern "C" void kernel_launch(void* const* d_in, const int* in_sizes, int n_in,
                              void* d_out, int out_size, void* d_ws, size_t ws_size,
                              hipStream_t stream)
{
    const float* X  = (const float*)d_in[0];
    const float* Wq = (const float*)d_in[1];
    const float* Wk = (const float*)d_in[2];
    const float* Wv = (const float*)d_in[3];
    float* out = (float*)d_out;

    const size_t qkv_elems = (size_t)BATCH * NHEADS * SEQ * HDIM;  // 4,194,304
    char* wsb = (char*)d_ws;
    float* ct  = (float*)wsb;                       // 0.5 MB
    float* st  = ct + (size_t)SEQ * HDIM;           // 0.5 MB
    u16* Xhi = (u16*)(st + (size_t)SEQ * HDIM);     // 8 MB
    u16* Xlo = Xhi + (size_t)NX;                    // 8 MB
    u16* Whi = Xlo + (size_t)NX;                    // 6 MB
    u16* Wlo = Whi + 3 * (size_t)NW;                // 6 MB
    u16* Qhi = Wlo + 3 * (size_t)NW;                // 8 MB
    u16* Qlo = Qhi + qkv_elems;                     // 8 MB
    u16* Khi = Qlo + qkv_elems;                     // 8 MB
    u16* Klo = Khi + qkv_elems;                     // 8 MB
    u16* Vhi = Klo + qkv_elems;                     // 8 MB
    u16* Vlo = Vhi + qkv_elems;                     // 8 MB   (total 77 MB)

    rope_tables_kernel<<<(SEQ * HDIM + 255) / 256, 256, 0, stream>>>(ct, st);

    // 14336 subtiles (8192 X + 3*2048 W), 4 per 256-thread block
    split_kernel<<<3584, 256, 0, stream>>>(
        X, Wq, Wk, Wv, Xhi, Xlo, Whi, Wlo);

    qkv_mfma_kernel<<<dim3(3 * (HID / 128) * ((BATCH * SEQ) / 128)), 256, 0, stream>>>(
        Xhi, Xlo, Whi, Wlo, ct, st, Qhi, Qlo, Khi, Klo, Vhi, Vlo);

    attn_kernel<<<dim3(SEQ / 128, NHEADS, BATCH), 256, 0, stream>>>(
        Qhi, Qlo, Khi, Klo, Vhi, Vlo, out);
}